// Round 6
// baseline (176.109 us; speedup 1.0000x reference)
//
#include <hip/hip_runtime.h>
#include <hip/hip_bf16.h>
#include <math.h>

#define DD 64
#define NSLICE 64          // edge slices; per-slice edges = 12500 (<2^15, u16-safe)
#define NMAXH 25000        // packed u16 counters for N=50000 nodes (100 KB LDS)

__device__ __forceinline__ int wave_incl_scan(int v, int lane) {
    #pragma unroll
    for (int d = 1; d < 64; d <<= 1) {
        int u = __shfl_up(v, d, 64);
        if (lane >= d) v += u;
    }
    return v;
}

// ---------------- histogram: grid = (slice, which), packed u16 LDS --------
__global__ __launch_bounds__(256) void hist_kernel(
    const int* __restrict__ src, const int* __restrict__ dst,
    unsigned short* __restrict__ hist_o, unsigned short* __restrict__ hist_i,
    int E, int N)
{
    __shared__ unsigned int h[NMAXH];
    int b = blockIdx.x, which = blockIdx.y, t = threadIdx.x;
    const int* col = which ? dst : src;
    int per = (E + NSLICE - 1) / NSLICE;
    int e0 = b * per, e1 = min(E, e0 + per);

    for (int j = t; j < NMAXH; j += 256) h[j] = 0u;
    __syncthreads();

    int eV = e1 & ~3;
    const int4* c4 = (const int4*)col;
    for (int q = (e0 >> 2) + t; q < (eV >> 2); q += 256) {
        int4 v = c4[q];
        unsigned u;
        u = (unsigned)v.x; atomicAdd(&h[u >> 1], 1u << ((u & 1) * 16));
        u = (unsigned)v.y; atomicAdd(&h[u >> 1], 1u << ((u & 1) * 16));
        u = (unsigned)v.z; atomicAdd(&h[u >> 1], 1u << ((u & 1) * 16));
        u = (unsigned)v.w; atomicAdd(&h[u >> 1], 1u << ((u & 1) * 16));
    }
    for (int e = eV + t; e < e1; e += 256) {
        unsigned u = (unsigned)col[e];
        atomicAdd(&h[u >> 1], 1u << ((u & 1) * 16));
    }
    __syncthreads();

    unsigned* orow = (unsigned*)((which ? hist_i : hist_o) + (size_t)b * N);
    int nw = (N + 1) >> 1;               // 25000 for N=50000
    for (int j = t; j < nw; j += 256) orow[j] = h[j];
}

// ------ fused reduce + block-level scan ------
__global__ __launch_bounds__(256) void reduce_scan_kernel(
    const unsigned short* __restrict__ hist_o, unsigned short* __restrict__ hist_i,
    int* __restrict__ offs, float* __restrict__ rs_odeg,
    float* __restrict__ rs_ideg, int* __restrict__ bsum, int N)
{
    int t = threadIdx.x, lane = t & 63, wid = t >> 6;
    int d = blockIdx.x * 256 + t;
    int run_o = 0, run_i = 0;
    if (d < N) {
        #pragma unroll 4
        for (int b = 0; b < NSLICE; ++b) {
            run_o += hist_o[(size_t)b * N + d];
            int tv = hist_i[(size_t)b * N + d];
            hist_i[(size_t)b * N + d] = (unsigned short)run_i;  // excl prefix over slices
            run_i += tv;
        }
    }
    int sv = wave_incl_scan(run_i, lane);
    __shared__ int ws[4], wso[4];
    if (lane == 63) ws[wid] = sv;
    __syncthreads();
    if (t == 0) {
        int a = 0;
        for (int w = 0; w < 4; ++w) { wso[w] = a; a += ws[w]; }
        bsum[blockIdx.x] = a;
    }
    __syncthreads();
    if (d < N) {
        offs[d] = sv - run_i + wso[wid];
        rs_odeg[d] = (run_o > 0) ? rsqrtf((float)run_o) : 0.0f;  // 0 (not inf): y-pass reads all rows
        rs_ideg[d] = (run_i > 0) ? rsqrtf((float)run_i) : 0.0f;
    }
}

// ------ scan_add + fused y = x * rs_odeg (node-wise) ------
__global__ __launch_bounds__(256) void scan_add_y_kernel(
    int* __restrict__ offs, const int* __restrict__ bsum,
    const float* __restrict__ x, const float* __restrict__ rs_odeg,
    float* __restrict__ y, int n)
{
    __shared__ int wsum[4];
    int t = threadIdx.x, lane = t & 63, wid = t >> 6;
    int v = (t < blockIdx.x) ? bsum[t] : 0;    // nb <= 256
    #pragma unroll
    for (int dlt = 32; dlt >= 1; dlt >>= 1) v += __shfl_xor(v, dlt, 64);
    if (lane == 0) wsum[wid] = v;
    __syncthreads();
    int pre = wsum[0] + wsum[1] + wsum[2] + wsum[3];
    int i = blockIdx.x * 256 + t;
    if (i < n) offs[i] += pre;

    // streaming y pass: rows [blockIdx*256, +256)
    int r0 = blockIdx.x * 256;
    int nr = min(256, n - r0);
    if (nr <= 0) return;
    const float4* x4 = (const float4*)(x + (size_t)r0 * DD);
    float4*       y4 = (float4*)(y + (size_t)r0 * DD);
    int tot = nr * (DD / 4);               // nr*16 float4s
    for (int q = t; q < tot; q += 256) {
        float w = rs_odeg[r0 + (q >> 4)];
        float4 vv = x4[q];
        vv.x *= w; vv.y *= w; vv.z *= w; vv.w *= w;
        y4[q] = vv;
    }
}

// ---- bucket fill: writes src index only; grid = (slice, segment) ----
#define SEG 16768
#define NSEG 3
__global__ __launch_bounds__(256) void bucket_kernel(
    const int* __restrict__ src, const int* __restrict__ dst,
    const int* __restrict__ offs, const unsigned short* __restrict__ hist_i,
    int* __restrict__ sorted_s, int E, int N)
{
    __shared__ int cur[SEG];
    int b = blockIdx.x, s = blockIdx.y, t = threadIdx.x;
    int per = (E + NSLICE - 1) / NSLICE;
    int e0 = b * per, e1 = min(E, e0 + per);
    int base = s * SEG;
    int segn = min(SEG, N - base);
    if (segn <= 0) return;

    for (int j = t; j < segn; j += 256)
        cur[j] = offs[base + j] + (int)hist_i[(size_t)b * N + base + j];
    __syncthreads();

    int eV = e1 & ~3;
    const int4* s4 = (const int4*)src;
    const int4* d4 = (const int4*)dst;
    for (int q = (e0 >> 2) + t; q < (eV >> 2); q += 256) {
        int4 dv = d4[q];
        int4 sv = s4[q];
        unsigned ux = (unsigned)(dv.x - base);
        unsigned uy = (unsigned)(dv.y - base);
        unsigned uz = (unsigned)(dv.z - base);
        unsigned uw = (unsigned)(dv.w - base);
        if (ux < (unsigned)segn) sorted_s[atomicAdd(&cur[ux], 1)] = sv.x;
        if (uy < (unsigned)segn) sorted_s[atomicAdd(&cur[uy], 1)] = sv.y;
        if (uz < (unsigned)segn) sorted_s[atomicAdd(&cur[uz], 1)] = sv.z;
        if (uw < (unsigned)segn) sorted_s[atomicAdd(&cur[uw], 1)] = sv.w;
    }
    for (int e = eV + t; e < e1; e += 256) {
        unsigned u = (unsigned)(dst[e] - base);
        if (u < (unsigned)segn)
            sorted_s[atomicAdd(&cur[u], 1)] = src[e];
    }
}

// ---- fused gather + FFN: 256 threads, 128 rows/block ----
// LDS = 16 KB (shared W buffer, time-multiplexed W1 then W2) + 34.8 KB sT
// -> 51.2 KB -> 3 blocks/CU (was 2 at 67.5 KB). W2 rides in 16 VGPRs
// across the gather phase; its global loads issue at kernel top so HBM
// latency hides under gather.
__global__ __launch_bounds__(256) void gather_ffn_kernel(
    const float* __restrict__ y,
    const int* __restrict__ sorted_s,
    const int* __restrict__ offs,
    const float* __restrict__ rs_ideg,
    const float* __restrict__ w1, const float* __restrict__ b1,
    const float* __restrict__ w2, const float* __restrict__ b2,
    float* __restrict__ out, int N, int E)
{
    __shared__ float sW[4096];          // W1 during GEMM1, W2 during GEMM2
    __shared__ float sT[128 * 68];

    int t = threadIdx.x;
    int row0 = blockIdx.x * 128;

    // stage W1 -> LDS; load W2 -> regs (written to LDS after GEMM1)
    const float4* w1v = (const float4*)w1;
    const float4* w2v = (const float4*)w2;
    float4 w2r[4];
    #pragma unroll
    for (int q = 0; q < 4; ++q) {
        ((float4*)sW)[t + q * 256] = w1v[t + q * 256];
        w2r[q] = w2v[t + q * 256];
    }

    // ---- gather phase ----
    int g = t >> 4, l16 = t & 15;
    int coff = l16 << 2;
    for (int r = g; r < 128; r += 16) {
        int d = row0 + r;
        float4 acc = make_float4(0.f, 0.f, 0.f, 0.f);
        if (d < N) {
            int beg = offs[d];
            int end = (d + 1 < N) ? offs[d + 1] : E;
            float nd = rs_ideg[d];
            int k = beg;
            for (; k + 8 <= end; k += 8) {
                int s0 = sorted_s[k + 0], s1 = sorted_s[k + 1];
                int s2 = sorted_s[k + 2], s3 = sorted_s[k + 3];
                int s4 = sorted_s[k + 4], s5 = sorted_s[k + 5];
                int s6 = sorted_s[k + 6], s7 = sorted_s[k + 7];
                const float4 r0 = *(const float4*)&y[(size_t)s0 * DD + coff];
                const float4 r1 = *(const float4*)&y[(size_t)s1 * DD + coff];
                const float4 r2 = *(const float4*)&y[(size_t)s2 * DD + coff];
                const float4 r3 = *(const float4*)&y[(size_t)s3 * DD + coff];
                const float4 r4 = *(const float4*)&y[(size_t)s4 * DD + coff];
                const float4 r5 = *(const float4*)&y[(size_t)s5 * DD + coff];
                const float4 r6 = *(const float4*)&y[(size_t)s6 * DD + coff];
                const float4 r7 = *(const float4*)&y[(size_t)s7 * DD + coff];
                acc.x += r0.x; acc.y += r0.y; acc.z += r0.z; acc.w += r0.w;
                acc.x += r1.x; acc.y += r1.y; acc.z += r1.z; acc.w += r1.w;
                acc.x += r2.x; acc.y += r2.y; acc.z += r2.z; acc.w += r2.w;
                acc.x += r3.x; acc.y += r3.y; acc.z += r3.z; acc.w += r3.w;
                acc.x += r4.x; acc.y += r4.y; acc.z += r4.z; acc.w += r4.w;
                acc.x += r5.x; acc.y += r5.y; acc.z += r5.z; acc.w += r5.w;
                acc.x += r6.x; acc.y += r6.y; acc.z += r6.z; acc.w += r6.w;
                acc.x += r7.x; acc.y += r7.y; acc.z += r7.z; acc.w += r7.w;
            }
            for (; k + 2 <= end; k += 2) {
                int s0 = sorted_s[k], s1 = sorted_s[k + 1];
                const float4 r0 = *(const float4*)&y[(size_t)s0 * DD + coff];
                const float4 r1 = *(const float4*)&y[(size_t)s1 * DD + coff];
                acc.x += r0.x; acc.y += r0.y; acc.z += r0.z; acc.w += r0.w;
                acc.x += r1.x; acc.y += r1.y; acc.z += r1.z; acc.w += r1.w;
            }
            if (k < end) {
                int s0 = sorted_s[k];
                const float4 r0 = *(const float4*)&y[(size_t)s0 * DD + coff];
                acc.x += r0.x; acc.y += r0.y; acc.z += r0.z; acc.w += r0.w;
            }
            acc.x *= nd; acc.y *= nd; acc.z *= nd; acc.w *= nd;
        }
        *(float4*)&sT[r * 68 + coff] = acc;
    }
    __syncthreads();

    // ---- FFN phase: slot = t>>3 (0..31), cb = (t&7)*8 ----
    int slot = t >> 3;
    int cb = (t & 7) << 3;

    float a[4][8];
    #pragma unroll
    for (int j = 0; j < 8; ++j) {
        float bv = b1[cb + j];
        a[0][j] = bv; a[1][j] = bv; a[2][j] = bv; a[3][j] = bv;
    }
    #pragma unroll 2
    for (int k = 0; k < 64; ++k) {
        float rv0 = sT[(slot      ) * 68 + k];
        float rv1 = sT[(slot + 32 ) * 68 + k];
        float rv2 = sT[(slot + 64 ) * 68 + k];
        float rv3 = sT[(slot + 96 ) * 68 + k];
        #pragma unroll
        for (int q = 0; q < 2; ++q) {
            float4 w = *(const float4*)&sW[k * 64 + cb + (q << 2)];
            a[0][q*4+0] = fmaf(rv0, w.x, a[0][q*4+0]); a[1][q*4+0] = fmaf(rv1, w.x, a[1][q*4+0]);
            a[2][q*4+0] = fmaf(rv2, w.x, a[2][q*4+0]); a[3][q*4+0] = fmaf(rv3, w.x, a[3][q*4+0]);
            a[0][q*4+1] = fmaf(rv0, w.y, a[0][q*4+1]); a[1][q*4+1] = fmaf(rv1, w.y, a[1][q*4+1]);
            a[2][q*4+1] = fmaf(rv2, w.y, a[2][q*4+1]); a[3][q*4+1] = fmaf(rv3, w.y, a[3][q*4+1]);
            a[0][q*4+2] = fmaf(rv0, w.z, a[0][q*4+2]); a[1][q*4+2] = fmaf(rv1, w.z, a[1][q*4+2]);
            a[2][q*4+2] = fmaf(rv2, w.z, a[2][q*4+2]); a[3][q*4+2] = fmaf(rv3, w.z, a[3][q*4+2]);
            a[0][q*4+3] = fmaf(rv0, w.w, a[0][q*4+3]); a[1][q*4+3] = fmaf(rv1, w.w, a[1][q*4+3]);
            a[2][q*4+3] = fmaf(rv2, w.w, a[2][q*4+3]); a[3][q*4+3] = fmaf(rv3, w.w, a[3][q*4+3]);
        }
    }
    #pragma unroll
    for (int i = 0; i < 4; ++i)
        #pragma unroll
        for (int j = 0; j < 8; ++j) {
            float v = a[i][j];
            a[i][j] = 0.5f * v * (1.0f + erff(v * 0.70710678118654752f));
        }
    __syncthreads();   // all GEMM1 reads of sT AND sW complete before overwrite
    #pragma unroll
    for (int i = 0; i < 4; ++i)
        #pragma unroll
        for (int q = 0; q < 2; ++q)
            *(float4*)&sT[(slot + 32 * i) * 68 + cb + (q << 2)] =
                make_float4(a[i][q*4+0], a[i][q*4+1], a[i][q*4+2], a[i][q*4+3]);
    #pragma unroll
    for (int q = 0; q < 4; ++q)
        ((float4*)sW)[t + q * 256] = w2r[q];     // W2 into the shared buffer
    __syncthreads();

    float o[4][8];
    #pragma unroll
    for (int j = 0; j < 8; ++j) {
        float bv = b2[cb + j];
        o[0][j] = bv; o[1][j] = bv; o[2][j] = bv; o[3][j] = bv;
    }
    #pragma unroll 2
    for (int k = 0; k < 64; ++k) {
        float hv0 = sT[(slot      ) * 68 + k];
        float hv1 = sT[(slot + 32 ) * 68 + k];
        float hv2 = sT[(slot + 64 ) * 68 + k];
        float hv3 = sT[(slot + 96 ) * 68 + k];
        #pragma unroll
        for (int q = 0; q < 2; ++q) {
            float4 w = *(const float4*)&sW[k * 64 + cb + (q << 2)];
            o[0][q*4+0] = fmaf(hv0, w.x, o[0][q*4+0]); o[1][q*4+0] = fmaf(hv1, w.x, o[1][q*4+0]);
            o[2][q*4+0] = fmaf(hv2, w.x, o[2][q*4+0]); o[3][q*4+0] = fmaf(hv3, w.x, o[3][q*4+0]);
            o[0][q*4+1] = fmaf(hv0, w.y, o[0][q*4+1]); o[1][q*4+1] = fmaf(hv1, w.y, o[1][q*4+1]);
            o[2][q*4+1] = fmaf(hv2, w.y, o[2][q*4+1]); o[3][q*4+1] = fmaf(hv3, w.y, o[3][q*4+1]);
            o[0][q*4+2] = fmaf(hv0, w.z, o[0][q*4+2]); o[1][q*4+2] = fmaf(hv1, w.z, o[1][q*4+2]);
            o[2][q*4+2] = fmaf(hv2, w.z, o[2][q*4+2]); o[3][q*4+2] = fmaf(hv3, w.z, o[3][q*4+2]);
            o[0][q*4+3] = fmaf(hv0, w.w, o[0][q*4+3]); o[1][q*4+3] = fmaf(hv1, w.w, o[1][q*4+3]);
            o[2][q*4+3] = fmaf(hv2, w.w, o[2][q*4+3]); o[3][q*4+3] = fmaf(hv3, w.w, o[3][q*4+3]);
        }
    }
    // direct store: thread covers rows slot+32i, cols cb..cb+7
    #pragma unroll
    for (int i = 0; i < 4; ++i) {
        int row = row0 + slot + 32 * i;
        if (row < N) {
            *(float4*)&out[(size_t)row * DD + cb    ] =
                make_float4(o[i][0], o[i][1], o[i][2], o[i][3]);
            *(float4*)&out[(size_t)row * DD + cb + 4] =
                make_float4(o[i][4], o[i][5], o[i][6], o[i][7]);
        }
    }
}

extern "C" void kernel_launch(void* const* d_in, const int* in_sizes, int n_in,
                              void* d_out, int out_size, void* d_ws, size_t ws_size,
                              hipStream_t stream)
{
    const float* x    = (const float*)d_in[0];
    const int*   esrc = (const int*)d_in[1];
    const int*   edst = (const int*)d_in[2];
    const float* w1   = (const float*)d_in[3];
    const float* b1   = (const float*)d_in[4];
    const float* w2   = (const float*)d_in[5];
    const float* b2   = (const float*)d_in[6];
    float* out = (float*)d_out;

    int N = in_sizes[0] / DD;   // 50000
    int E = in_sizes[1];        // 800000
    int nb = (N + 255) / 256;   // 196

    // workspace layout (d_ws is >=256B aligned): y first (float4 accesses)
    float*          y          = (float*)d_ws;                       // N*DD
    int*            sorted_s   = (int*)(y + (size_t)N * DD);         // E
    int*            offs       = sorted_s + E;                       // N
    float*          rs_odeg    = (float*)(offs + N);                 // N
    float*          rs_ideg    = rs_odeg + N;                        // N
    int*            bsum       = (int*)(rs_ideg + N);                // 256
    unsigned short* hist_o     = (unsigned short*)(bsum + 256);      // NSLICE*N
    unsigned short* hist_i     = hist_o + (size_t)NSLICE * N;        // NSLICE*N

    hist_kernel<<<dim3(NSLICE, 2), 256, 0, stream>>>(esrc, edst, hist_o, hist_i, E, N);
    reduce_scan_kernel<<<nb, 256, 0, stream>>>(hist_o, hist_i, offs, rs_odeg, rs_ideg, bsum, N);
    scan_add_y_kernel<<<nb, 256, 0, stream>>>(offs, bsum, x, rs_odeg, y, N);
    bucket_kernel<<<dim3(NSLICE, NSEG), 256, 0, stream>>>(esrc, edst, offs, hist_i, sorted_s, E, N);
    gather_ffn_kernel<<<(N + 127) / 128, 256, 0, stream>>>(y, sorted_s, offs, rs_ideg,
                                                           w1, b1, w2, b2, out, N, E);
}

// Round 7
// 167.576 us; speedup vs baseline: 1.0509x; 1.0509x over previous
//
#include <hip/hip_runtime.h>
#include <hip/hip_bf16.h>
#include <math.h>

#define DD 64
#define NSLICE 64          // edge slices; per-slice edges = 12500 (<2^15, u16-safe)
#define NMAXH 25000        // packed u16 counters for N=50000 nodes (100 KB LDS)

__device__ __forceinline__ int wave_incl_scan(int v, int lane) {
    #pragma unroll
    for (int d = 1; d < 64; d <<= 1) {
        int u = __shfl_up(v, d, 64);
        if (lane >= d) v += u;
    }
    return v;
}

// ---------------- histogram: grid = (slice, which), packed u16 LDS --------
__global__ __launch_bounds__(256) void hist_kernel(
    const int* __restrict__ src, const int* __restrict__ dst,
    unsigned short* __restrict__ hist_o, unsigned short* __restrict__ hist_i,
    int E, int N)
{
    __shared__ unsigned int h[NMAXH];
    int b = blockIdx.x, which = blockIdx.y, t = threadIdx.x;
    const int* col = which ? dst : src;
    int per = (E + NSLICE - 1) / NSLICE;
    int e0 = b * per, e1 = min(E, e0 + per);

    for (int j = t; j < NMAXH; j += 256) h[j] = 0u;
    __syncthreads();

    int eV = e1 & ~3;
    const int4* c4 = (const int4*)col;
    for (int q = (e0 >> 2) + t; q < (eV >> 2); q += 256) {
        int4 v = c4[q];
        unsigned u;
        u = (unsigned)v.x; atomicAdd(&h[u >> 1], 1u << ((u & 1) * 16));
        u = (unsigned)v.y; atomicAdd(&h[u >> 1], 1u << ((u & 1) * 16));
        u = (unsigned)v.z; atomicAdd(&h[u >> 1], 1u << ((u & 1) * 16));
        u = (unsigned)v.w; atomicAdd(&h[u >> 1], 1u << ((u & 1) * 16));
    }
    for (int e = eV + t; e < e1; e += 256) {
        unsigned u = (unsigned)col[e];
        atomicAdd(&h[u >> 1], 1u << ((u & 1) * 16));
    }
    __syncthreads();

    unsigned* orow = (unsigned*)((which ? hist_i : hist_o) + (size_t)b * N);
    int nw = (N + 1) >> 1;               // 25000 for N=50000
    for (int j = t; j < nw; j += 256) orow[j] = h[j];
}

// ------ fused reduce + block-level scan ------
__global__ __launch_bounds__(256) void reduce_scan_kernel(
    const unsigned short* __restrict__ hist_o, unsigned short* __restrict__ hist_i,
    int* __restrict__ offs, float* __restrict__ rs_odeg,
    float* __restrict__ rs_ideg, int* __restrict__ bsum, int N)
{
    int t = threadIdx.x, lane = t & 63, wid = t >> 6;
    int d = blockIdx.x * 256 + t;
    int run_o = 0, run_i = 0;
    if (d < N) {
        #pragma unroll 4
        for (int b = 0; b < NSLICE; ++b) {
            run_o += hist_o[(size_t)b * N + d];
            int tv = hist_i[(size_t)b * N + d];
            hist_i[(size_t)b * N + d] = (unsigned short)run_i;  // excl prefix over slices
            run_i += tv;
        }
    }
    int sv = wave_incl_scan(run_i, lane);
    __shared__ int ws[4], wso[4];
    if (lane == 63) ws[wid] = sv;
    __syncthreads();
    if (t == 0) {
        int a = 0;
        for (int w = 0; w < 4; ++w) { wso[w] = a; a += ws[w]; }
        bsum[blockIdx.x] = a;
    }
    __syncthreads();
    if (d < N) {
        offs[d] = sv - run_i + wso[wid];
        rs_odeg[d] = (run_o > 0) ? rsqrtf((float)run_o) : 0.0f;  // 0 (not inf): y-pass reads all rows
        rs_ideg[d] = (run_i > 0) ? rsqrtf((float)run_i) : 0.0f;
    }
}

// ------ scan_add + fused y = x * rs_odeg (node-wise) ------
__global__ __launch_bounds__(256) void scan_add_y_kernel(
    int* __restrict__ offs, const int* __restrict__ bsum,
    const float* __restrict__ x, const float* __restrict__ rs_odeg,
    float* __restrict__ y, int n)
{
    __shared__ int wsum[4];
    int t = threadIdx.x, lane = t & 63, wid = t >> 6;
    int v = (t < blockIdx.x) ? bsum[t] : 0;    // nb <= 256
    #pragma unroll
    for (int dlt = 32; dlt >= 1; dlt >>= 1) v += __shfl_xor(v, dlt, 64);
    if (lane == 0) wsum[wid] = v;
    __syncthreads();
    int pre = wsum[0] + wsum[1] + wsum[2] + wsum[3];
    int i = blockIdx.x * 256 + t;
    if (i < n) offs[i] += pre;

    // streaming y pass: rows [blockIdx*256, +256)
    int r0 = blockIdx.x * 256;
    int nr = min(256, n - r0);
    if (nr <= 0) return;
    const float4* x4 = (const float4*)(x + (size_t)r0 * DD);
    float4*       y4 = (float4*)(y + (size_t)r0 * DD);
    int tot = nr * (DD / 4);               // nr*16 float4s
    for (int q = t; q < tot; q += 256) {
        float w = rs_odeg[r0 + (q >> 4)];
        float4 vv = x4[q];
        vv.x *= w; vv.y *= w; vv.z *= w; vv.w *= w;
        y4[q] = vv;
    }
}

// ---- bucket fill: writes src index only; grid = (slice, segment) ----
#define SEG 16768
#define NSEG 3
__global__ __launch_bounds__(256) void bucket_kernel(
    const int* __restrict__ src, const int* __restrict__ dst,
    const int* __restrict__ offs, const unsigned short* __restrict__ hist_i,
    int* __restrict__ sorted_s, int E, int N)
{
    __shared__ int cur[SEG];
    int b = blockIdx.x, s = blockIdx.y, t = threadIdx.x;
    int per = (E + NSLICE - 1) / NSLICE;
    int e0 = b * per, e1 = min(E, e0 + per);
    int base = s * SEG;
    int segn = min(SEG, N - base);
    if (segn <= 0) return;

    for (int j = t; j < segn; j += 256)
        cur[j] = offs[base + j] + (int)hist_i[(size_t)b * N + base + j];
    __syncthreads();

    int eV = e1 & ~3;
    const int4* s4 = (const int4*)src;
    const int4* d4 = (const int4*)dst;
    for (int q = (e0 >> 2) + t; q < (eV >> 2); q += 256) {
        int4 dv = d4[q];
        int4 sv = s4[q];
        unsigned ux = (unsigned)(dv.x - base);
        unsigned uy = (unsigned)(dv.y - base);
        unsigned uz = (unsigned)(dv.z - base);
        unsigned uw = (unsigned)(dv.w - base);
        if (ux < (unsigned)segn) sorted_s[atomicAdd(&cur[ux], 1)] = sv.x;
        if (uy < (unsigned)segn) sorted_s[atomicAdd(&cur[uy], 1)] = sv.y;
        if (uz < (unsigned)segn) sorted_s[atomicAdd(&cur[uz], 1)] = sv.z;
        if (uw < (unsigned)segn) sorted_s[atomicAdd(&cur[uw], 1)] = sv.w;
    }
    for (int e = eV + t; e < e1; e += 256) {
        unsigned u = (unsigned)(dst[e] - base);
        if (u < (unsigned)segn)
            sorted_s[atomicAdd(&cur[u], 1)] = src[e];
    }
}

// ---- fused gather + FFN: 256 threads, 64 rows/block (grid 782) ----
// LDS = 16 KB time-shared W buffer + 17.4 KB sT = 33.4 KB -> 4 blocks/CU;
// 782 blocks => ~3 blocks/CU all co-resident => ~12 waves/CU during the
// latency-bound gather phase (was 6.1 at 128 rows/block -- grid-limited).
__global__ __launch_bounds__(256) void gather_ffn_kernel(
    const float* __restrict__ y,
    const int* __restrict__ sorted_s,
    const int* __restrict__ offs,
    const float* __restrict__ rs_ideg,
    const float* __restrict__ w1, const float* __restrict__ b1,
    const float* __restrict__ w2, const float* __restrict__ b2,
    float* __restrict__ out, int N, int E)
{
    __shared__ float sW[4096];          // W1 during GEMM1, W2 during GEMM2
    __shared__ float sT[64 * 68];

    int t = threadIdx.x;
    int row0 = blockIdx.x * 64;

    // stage W1 -> LDS; load W2 -> regs (written to LDS after GEMM1)
    const float4* w1v = (const float4*)w1;
    const float4* w2v = (const float4*)w2;
    float4 w2r[4];
    #pragma unroll
    for (int q = 0; q < 4; ++q) {
        ((float4*)sW)[t + q * 256] = w1v[t + q * 256];
        w2r[q] = w2v[t + q * 256];
    }

    // ---- gather phase: 16-lane subgroup per node, 4 nodes per subgroup ----
    int g = t >> 4, l16 = t & 15;
    int coff = l16 << 2;
    for (int r = g; r < 64; r += 16) {
        int d = row0 + r;
        float4 acc = make_float4(0.f, 0.f, 0.f, 0.f);
        if (d < N) {
            int beg = offs[d];
            int end = (d + 1 < N) ? offs[d + 1] : E;
            float nd = rs_ideg[d];
            int k = beg;
            for (; k + 8 <= end; k += 8) {
                int s0 = sorted_s[k + 0], s1 = sorted_s[k + 1];
                int s2 = sorted_s[k + 2], s3 = sorted_s[k + 3];
                int s4 = sorted_s[k + 4], s5 = sorted_s[k + 5];
                int s6 = sorted_s[k + 6], s7 = sorted_s[k + 7];
                const float4 r0 = *(const float4*)&y[(size_t)s0 * DD + coff];
                const float4 r1 = *(const float4*)&y[(size_t)s1 * DD + coff];
                const float4 r2 = *(const float4*)&y[(size_t)s2 * DD + coff];
                const float4 r3 = *(const float4*)&y[(size_t)s3 * DD + coff];
                const float4 r4 = *(const float4*)&y[(size_t)s4 * DD + coff];
                const float4 r5 = *(const float4*)&y[(size_t)s5 * DD + coff];
                const float4 r6 = *(const float4*)&y[(size_t)s6 * DD + coff];
                const float4 r7 = *(const float4*)&y[(size_t)s7 * DD + coff];
                acc.x += r0.x; acc.y += r0.y; acc.z += r0.z; acc.w += r0.w;
                acc.x += r1.x; acc.y += r1.y; acc.z += r1.z; acc.w += r1.w;
                acc.x += r2.x; acc.y += r2.y; acc.z += r2.z; acc.w += r2.w;
                acc.x += r3.x; acc.y += r3.y; acc.z += r3.z; acc.w += r3.w;
                acc.x += r4.x; acc.y += r4.y; acc.z += r4.z; acc.w += r4.w;
                acc.x += r5.x; acc.y += r5.y; acc.z += r5.z; acc.w += r5.w;
                acc.x += r6.x; acc.y += r6.y; acc.z += r6.z; acc.w += r6.w;
                acc.x += r7.x; acc.y += r7.y; acc.z += r7.z; acc.w += r7.w;
            }
            for (; k + 2 <= end; k += 2) {
                int s0 = sorted_s[k], s1 = sorted_s[k + 1];
                const float4 r0 = *(const float4*)&y[(size_t)s0 * DD + coff];
                const float4 r1 = *(const float4*)&y[(size_t)s1 * DD + coff];
                acc.x += r0.x; acc.y += r0.y; acc.z += r0.z; acc.w += r0.w;
                acc.x += r1.x; acc.y += r1.y; acc.z += r1.z; acc.w += r1.w;
            }
            if (k < end) {
                int s0 = sorted_s[k];
                const float4 r0 = *(const float4*)&y[(size_t)s0 * DD + coff];
                acc.x += r0.x; acc.y += r0.y; acc.z += r0.z; acc.w += r0.w;
            }
            acc.x *= nd; acc.y *= nd; acc.z *= nd; acc.w *= nd;
        }
        *(float4*)&sT[r * 68 + coff] = acc;
    }
    __syncthreads();

    // ---- FFN phase: slot = t>>3 (0..31) covers rows slot, slot+32 ----
    int slot = t >> 3;
    int cb = (t & 7) << 3;

    float a[2][8];
    #pragma unroll
    for (int j = 0; j < 8; ++j) {
        float bv = b1[cb + j];
        a[0][j] = bv; a[1][j] = bv;
    }
    #pragma unroll 2
    for (int k = 0; k < 64; ++k) {
        float rv0 = sT[(slot      ) * 68 + k];
        float rv1 = sT[(slot + 32 ) * 68 + k];
        #pragma unroll
        for (int q = 0; q < 2; ++q) {
            float4 w = *(const float4*)&sW[k * 64 + cb + (q << 2)];
            a[0][q*4+0] = fmaf(rv0, w.x, a[0][q*4+0]); a[1][q*4+0] = fmaf(rv1, w.x, a[1][q*4+0]);
            a[0][q*4+1] = fmaf(rv0, w.y, a[0][q*4+1]); a[1][q*4+1] = fmaf(rv1, w.y, a[1][q*4+1]);
            a[0][q*4+2] = fmaf(rv0, w.z, a[0][q*4+2]); a[1][q*4+2] = fmaf(rv1, w.z, a[1][q*4+2]);
            a[0][q*4+3] = fmaf(rv0, w.w, a[0][q*4+3]); a[1][q*4+3] = fmaf(rv1, w.w, a[1][q*4+3]);
        }
    }
    #pragma unroll
    for (int i = 0; i < 2; ++i)
        #pragma unroll
        for (int j = 0; j < 8; ++j) {
            float v = a[i][j];
            a[i][j] = 0.5f * v * (1.0f + erff(v * 0.70710678118654752f));
        }
    __syncthreads();   // all GEMM1 reads of sT AND sW complete before overwrite
    #pragma unroll
    for (int i = 0; i < 2; ++i)
        #pragma unroll
        for (int q = 0; q < 2; ++q)
            *(float4*)&sT[(slot + 32 * i) * 68 + cb + (q << 2)] =
                make_float4(a[i][q*4+0], a[i][q*4+1], a[i][q*4+2], a[i][q*4+3]);
    #pragma unroll
    for (int q = 0; q < 4; ++q)
        ((float4*)sW)[t + q * 256] = w2r[q];     // W2 into the shared buffer
    __syncthreads();

    float o[2][8];
    #pragma unroll
    for (int j = 0; j < 8; ++j) {
        float bv = b2[cb + j];
        o[0][j] = bv; o[1][j] = bv;
    }
    #pragma unroll 2
    for (int k = 0; k < 64; ++k) {
        float hv0 = sT[(slot      ) * 68 + k];
        float hv1 = sT[(slot + 32 ) * 68 + k];
        #pragma unroll
        for (int q = 0; q < 2; ++q) {
            float4 w = *(const float4*)&sW[k * 64 + cb + (q << 2)];
            o[0][q*4+0] = fmaf(hv0, w.x, o[0][q*4+0]); o[1][q*4+0] = fmaf(hv1, w.x, o[1][q*4+0]);
            o[0][q*4+1] = fmaf(hv0, w.y, o[0][q*4+1]); o[1][q*4+1] = fmaf(hv1, w.y, o[1][q*4+1]);
            o[0][q*4+2] = fmaf(hv0, w.z, o[0][q*4+2]); o[1][q*4+2] = fmaf(hv1, w.z, o[1][q*4+2]);
            o[0][q*4+3] = fmaf(hv0, w.w, o[0][q*4+3]); o[1][q*4+3] = fmaf(hv1, w.w, o[1][q*4+3]);
        }
    }
    // direct store: thread covers rows slot, slot+32, cols cb..cb+7
    #pragma unroll
    for (int i = 0; i < 2; ++i) {
        int row = row0 + slot + 32 * i;
        if (row < N) {
            *(float4*)&out[(size_t)row * DD + cb    ] =
                make_float4(o[i][0], o[i][1], o[i][2], o[i][3]);
            *(float4*)&out[(size_t)row * DD + cb + 4] =
                make_float4(o[i][4], o[i][5], o[i][6], o[i][7]);
        }
    }
}

extern "C" void kernel_launch(void* const* d_in, const int* in_sizes, int n_in,
                              void* d_out, int out_size, void* d_ws, size_t ws_size,
                              hipStream_t stream)
{
    const float* x    = (const float*)d_in[0];
    const int*   esrc = (const int*)d_in[1];
    const int*   edst = (const int*)d_in[2];
    const float* w1   = (const float*)d_in[3];
    const float* b1   = (const float*)d_in[4];
    const float* w2   = (const float*)d_in[5];
    const float* b2   = (const float*)d_in[6];
    float* out = (float*)d_out;

    int N = in_sizes[0] / DD;   // 50000
    int E = in_sizes[1];        // 800000
    int nb = (N + 255) / 256;   // 196

    // workspace layout (d_ws is >=256B aligned): y first (float4 accesses)
    float*          y          = (float*)d_ws;                       // N*DD
    int*            sorted_s   = (int*)(y + (size_t)N * DD);         // E
    int*            offs       = sorted_s + E;                       // N
    float*          rs_odeg    = (float*)(offs + N);                 // N
    float*          rs_ideg    = rs_odeg + N;                        // N
    int*            bsum       = (int*)(rs_ideg + N);                // 256
    unsigned short* hist_o     = (unsigned short*)(bsum + 256);      // NSLICE*N
    unsigned short* hist_i     = hist_o + (size_t)NSLICE * N;        // NSLICE*N

    hist_kernel<<<dim3(NSLICE, 2), 256, 0, stream>>>(esrc, edst, hist_o, hist_i, E, N);
    reduce_scan_kernel<<<nb, 256, 0, stream>>>(hist_o, hist_i, offs, rs_odeg, rs_ideg, bsum, N);
    scan_add_y_kernel<<<nb, 256, 0, stream>>>(offs, bsum, x, rs_odeg, y, N);
    bucket_kernel<<<dim3(NSLICE, NSEG), 256, 0, stream>>>(esrc, edst, offs, hist_i, sorted_s, E, N);
    gather_ffn_kernel<<<(N + 63) / 64, 256, 0, stream>>>(y, sorted_s, offs, rs_ideg,
                                                         w1, b1, w2, b2, out, N, E);
}